// Round 13
// baseline (3320.361 us; speedup 1.0000x reference)
//
#include <hip/hip_runtime.h>
#include <cstdint>

#define T_STEPS 1024
#define BATCH   32
#define DIM     1024
#define RANK    128
#define BD      (BATCH*DIM)            // 32768
#define TBD     ((size_t)T_STEPS*BD)   // 33554432

typedef _Float16 half2v __attribute__((ext_vector_type(2)));

__device__ __forceinline__ float dot2f(uint32_t a, uint32_t b, float acc) {
#if __has_builtin(__builtin_amdgcn_fdot2)
  return __builtin_amdgcn_fdot2(__builtin_bit_cast(half2v, a),
                                __builtin_bit_cast(half2v, b), acc, false);
#else
  half2v xx = __builtin_bit_cast(half2v, a);
  half2v yy = __builtin_bit_cast(half2v, b);
  return acc + (float)xx[0]*(float)yy[0] + (float)xx[1]*(float)yy[1];
#endif
}

__device__ __forceinline__ float dot2x4(uint4 w, uint4 h, float acc) {
  acc = dot2f(w.x, h.x, acc); acc = dot2f(w.y, h.y, acc);
  acc = dot2f(w.z, h.z, acc); acc = dot2f(w.w, h.w, acc);
  return acc;
}

__device__ __forceinline__ uint16_t f16b(float x) {
  _Float16 h = (_Float16)x;
  return __builtin_bit_cast(unsigned short, h);
}
__device__ __forceinline__ uint32_t pack2(float a, float b) {
  return (uint32_t)f16b(a) | ((uint32_t)f16b(b) << 16);
}
__device__ __forceinline__ float fast_tanh(float x) {
  float e = __expf(2.0f*x);
  return 1.0f - 2.0f/(e + 1.0f);
}
__device__ __forceinline__ float fast_silu(float zz) {
  return zz / (1.0f + __expf(-zz));
}

__device__ __forceinline__ void pin4(uint4 &v) {
  asm volatile("" : "+v"(v.x), "+v"(v.y), "+v"(v.z), "+v"(v.w));
}

// quad_perm broadcast of lane K (0..3) within each quad — VALU pipe, no LDS.
template<int K>
__device__ __forceinline__ uint32_t qbcast(uint32_t v) {
  return (uint32_t)__builtin_amdgcn_mov_dpp((int)v, K*0x55, 0xf, 0xf, true);
}
template<int K>
__device__ __forceinline__ uint4 qbcast4(uint4 v) {
  uint4 r;
  r.x = qbcast<K>(v.x); r.y = qbcast<K>(v.y);
  r.z = qbcast<K>(v.z); r.w = qbcast<K>(v.w);
  return r;
}
template<int CTRL>
__device__ __forceinline__ float dpp_xorf(float v) {
  int t = __builtin_amdgcn_mov_dpp(__builtin_bit_cast(int, v), CTRL, 0xf, 0xf, true);
  return __builtin_bit_cast(float, t);
}

// barrier that does NOT drain vmcnt (only LDS ordering needed between phases)
__device__ __forceinline__ void lds_barrier() {
  asm volatile("s_waitcnt lgkmcnt(0)" ::: "memory");
  __builtin_amdgcn_s_barrier();
  __builtin_amdgcn_sched_barrier(0);
}

// ---------------------------------------------------------------------------
// K0: pack weights to f16 pairs in ws (s folded into U), h0 -> h-slot 0.
// ws layout (uint32 words):
//   [0]      vhw  [128][512]   V_h f16 pairs (word = adjacent d-pair)
//   [65536]  uqs  [26][512][4] U'_h STREAM layout (interleaved col pairs):
//                              chunk J<13: row 2*lane words 4J..4J+3
//                              chunk J>=13: row 2*lane+1 words 4(J-13)..+3
//                              (only words 0..51; lane-stride 16B = coalesced)
//   [118784] ures [1024][12]   U'_h words 52..63 (row-major; rec stages to LDS)
//   [131072] vxw  [128][512]
//   [196608] uxw  [1024][64]   (plain pair layout, used by inp_kernel)
// U'_h word k of row d = pack(U[d][k]*s[k], U[d][k+64]*s[k+64]).
// ---------------------------------------------------------------------------
__global__ void prep_kernel(const float* __restrict__ Uh, const float* __restrict__ Vh,
                            const float* __restrict__ sh, const float* __restrict__ Ux,
                            const float* __restrict__ Vx, const float* __restrict__ sx,
                            const float* __restrict__ h0, uint32_t* __restrict__ ws32,
                            float* __restrict__ hout) {
  int i = blockIdx.x*blockDim.x + threadIdx.x;
  int n = gridDim.x*blockDim.x;
  for (int p = i; p < 65536; p += n) {
    int r = p >> 9, dp = p & 511;
    ws32[p] = pack2(Vh[r*1024 + 2*dp], Vh[r*1024 + 2*dp + 1]);
  }
  for (int p = i; p < 65536; p += n) {
    int d = p >> 6, k = p & 63;
    uint32_t w = pack2(Uh[d*128 + k]      * sh[k],
                       Uh[d*128 + 64 + k] * sh[64 + k]);
    if (k < 52) {
      int J = (k >> 2) + 13*(d & 1);
      ws32[65536 + J*2048 + (d >> 1)*4 + (k & 3)] = w;
    } else {
      ws32[118784 + d*12 + (k - 52)] = w;
    }
  }
  for (int p = i; p < 65536; p += n) {
    int r = p >> 9, dp = p & 511;
    ws32[131072 + p] = pack2(Vx[r*1024 + 2*dp], Vx[r*1024 + 2*dp + 1]);
  }
  for (int p = i; p < 65536; p += n) {
    int d = p >> 6, rp = p & 63;
    ws32[196608 + p] = pack2(Ux[d*128 + 2*rp]   * sx[2*rp],
                             Ux[d*128 + 2*rp+1] * sx[2*rp+1]);
  }
  for (int p = i; p < BD; p += n) hout[p] = h0[p];
}

// ---------------------------------------------------------------------------
// K1: input branch. One WG per timestep t. (unchanged)
// ---------------------------------------------------------------------------
__global__ __launch_bounds__(512, 4) void inp_kernel(
    const float* __restrict__ x, const uint32_t* __restrict__ ws32,
    const float* __restrict__ bias, float* __restrict__ hout) {
  const int t = blockIdx.x;
  const int l = threadIdx.x;  // 0..511
  __shared__ __attribute__((aligned(16))) uint32_t xs[32*516];
  __shared__ __attribute__((aligned(16))) uint16_t svx[BATCH*RANK];

  const float4* xg = (const float4*)(x + (size_t)t*BD);
  #pragma unroll
  for (int k = 0; k < 16; k++) {
    int i = l + 512*k;
    float4 v = xg[i];
    int bb = i >> 8;
    int d4 = i & 255;
    xs[bb*516 + d4*2]     = pack2(v.x, v.y);
    xs[bb*516 + d4*2 + 1] = pack2(v.z, v.w);
  }
  __syncthreads();

  const int q4 = l & 3;
  const int r  = l >> 2;
  const uint4* wrow = (const uint4*)(ws32 + 131072 + r*512);
  float acc0[8], acc1[8];
  #pragma unroll
  for (int bi = 0; bi < 8; bi++) { acc0[bi] = 0.f; acc1[bi] = 0.f; }
  #pragma unroll 4
  for (int J = 0; J < 128; J += 2) {
    uint4 w0 = wrow[J];
    uint4 w1 = wrow[J+1];
    #pragma unroll
    for (int bi = 0; bi < 8; bi++) {
      const uint4* xrow = (const uint4*)(xs + (4*bi + q4)*516);
      uint4 h0v = xrow[J];
      acc0[bi] = dot2f(w0.x, h0v.x, acc0[bi]);
      acc0[bi] = dot2f(w0.y, h0v.y, acc0[bi]);
      acc0[bi] = dot2f(w0.z, h0v.z, acc0[bi]);
      acc0[bi] = dot2f(w0.w, h0v.w, acc0[bi]);
      uint4 h1v = xrow[J+1];
      acc1[bi] = dot2f(w1.x, h1v.x, acc1[bi]);
      acc1[bi] = dot2f(w1.y, h1v.y, acc1[bi]);
      acc1[bi] = dot2f(w1.z, h1v.z, acc1[bi]);
      acc1[bi] = dot2f(w1.w, h1v.w, acc1[bi]);
    }
  }
  #pragma unroll
  for (int bi = 0; bi < 8; bi++)
    svx[(4*bi + q4)*RANK + r] = f16b(acc0[bi] + acc1[bi]);
  __syncthreads();

  const uint4* svx4 = (const uint4*)svx;
  float accb[BATCH];
  #pragma unroll 1
  for (int dd = 0; dd < 2; dd++) {
    int d = l + dd*512;
    const uint4* urow = (const uint4*)(ws32 + 196608 + d*64);
    #pragma unroll
    for (int bi = 0; bi < BATCH; bi++) accb[bi] = 0.f;
    #pragma unroll
    for (int RP = 0; RP < 16; RP++) {
      uint4 w = urow[RP];
      #pragma unroll
      for (int bi = 0; bi < BATCH; bi++) {
        uint4 sv = svx4[bi*16 + RP];
        accb[bi] = dot2f(w.x, sv.x, accb[bi]);
        accb[bi] = dot2f(w.y, sv.y, accb[bi]);
        accb[bi] = dot2f(w.z, sv.z, accb[bi]);
        accb[bi] = dot2f(w.w, sv.w, accb[bi]);
      }
    }
    float bv = bias[d];
    float* cslot = hout + (size_t)(t+1)*BD + d;
    #pragma unroll
    for (int bi = 0; bi < BATCH; bi++)
      cslot[(size_t)bi*DIM] = accb[bi] + bv;
  }
}

// ---------------------------------------------------------------------------
// K2: recurrence v13 = R9 (1952us, best) with the streamed bytes reduced.
// One WG (512 thr = 8 waves, 2 waves/SIMD) per batch b. 128-reg bucket is
// accepted as fact (R4-R11); design fits it honestly:
//   regs  80 w: V rows 8R8+0..4 (pinned)
//   LDS  147 KB: V rows 8R8+5..7 (96K) + U words 52..63 lane-major (48K)
//   STREAM 208 KB/step: U words 0..51 from the coalesced uqs layout
//   (R9 streamed ~250 KB from a row-major layout via compiler remat).
// Streamed loads are written inline at their consuming quarter; if LICM
// hoists them the allocator remats at use points = same schedule.
// ---------------------------------------------------------------------------
__global__ __attribute__((amdgpu_flat_work_group_size(512, 512),
                          amdgpu_waves_per_eu(2, 2)))
void rec_kernel(
    const uint32_t* __restrict__ ws32, const float* __restrict__ z,
    float* __restrict__ outb) {
  const int b  = blockIdx.x;
  const int l  = threadIdx.x;  // 0..511
  const int W  = l & 31;
  const int R8 = l >> 5;       // 0..15
  const int m  = l & 3;
  float* hout = outb + TBD;
  const uint4* vhw4 = (const uint4*)ws32;              // V: row stride 128 uint4
  const uint4* uqs4 = (const uint4*)(ws32 + 65536);    // stream chunks [26][512]
  const uint4* ures4 = (const uint4*)(ws32 + 118784);  // [1024][3] words 52..63

  __shared__ __attribute__((aligned(16))) uint4    vlds[6144];   // 96 KB
  __shared__ __attribute__((aligned(16))) uint4    ulds[3072];   // 48 KB
  __shared__ __attribute__((aligned(16))) uint4    hbuf[32*5];   // 2.5 KB staggered
  __shared__ __attribute__((aligned(16))) uint32_t svh32[64];    // 256 B

  // V rows 8R8+0..4, window [16W,16W+16) pairs -> VGPRs (80 words, pinned)
  uint4 vw[5][4];
  #pragma unroll
  for (int r = 0; r < 5; r++) {
    #pragma unroll
    for (int c = 0; c < 4; c++) vw[r][c] = vhw4[(8*R8 + r)*128 + W*4 + c];
  }
  #pragma unroll
  for (int r = 0; r < 5; r++) {
    #pragma unroll
    for (int c = 0; c < 4; c++) pin4(vw[r][c]);
  }
  // V rows 8R8+5,6,7 -> vlds (interleaved: idx = R8*384 + rr*128 + c*32 + W)
  #pragma unroll
  for (int rr = 0; rr < 3; rr++) {
    #pragma unroll
    for (int c = 0; c < 4; c++)
      vlds[R8*384 + rr*128 + c*32 + W] = vhw4[(8*R8 + 5 + rr)*128 + W*4 + c];
  }
  // U words 52..63 of rows 2l (slots 0..2) and 2l+1 (slots 3..5) -> ulds
  #pragma unroll
  for (int j = 0; j < 3; j++) {
    ulds[j*512 + l]       = ures4[(2*l)*3 + j];
    ulds[(3+j)*512 + l]   = ures4[(2*l+1)*3 + j];
  }
  // init hbuf from h0 (pair p=l at word 20*(p>>4) + (p&15))
  {
    const float2 v = ((const float2*)(hout + (size_t)b*DIM))[l];
    ((uint32_t*)hbuf)[20*(l>>4) + (l&15)] = pack2(v.x, v.y);
  }
  __syncthreads();

  const float2* zp2 = (const float2*)(z + (size_t)b*DIM) + l;
  float2*       cp2 = (float2*)(hout + BD + (size_t)b*DIM) + l;
  float2*       op2 = (float2*)(outb + (size_t)b*DIM) + l;
  const uint4*  hb4  = hbuf + W*5;
  const uint4*  svh4 = (const uint4*)svh32;
  const int vbase = R8*384;

  #pragma unroll 1
  for (int t = 0; t < T_STEPS; t++) {
    // ---- issue c (slot t+1) and z (slot t) loads: consumed in phase B ----
    float2 cc = *cp2;
    float2 zz = *zp2;

    // ---- phase A: 8 rows (5 reg + 3 LDS) x 16-pair window ----
    float a[8] = {0.f,0.f,0.f,0.f,0.f,0.f,0.f,0.f};
    #pragma unroll
    for (int c = 0; c < 4; c++) {
      uint4 hvc = hb4[c];
      uint4 vA = vlds[vbase + c*32 + W];
      uint4 vB = vlds[vbase + 128 + c*32 + W];
      uint4 vC = vlds[vbase + 256 + c*32 + W];
      a[0] = dot2x4(vw[0][c], hvc, a[0]);
      a[1] = dot2x4(vw[1][c], hvc, a[1]);
      a[2] = dot2x4(vw[2][c], hvc, a[2]);
      a[3] = dot2x4(vw[3][c], hvc, a[3]);
      a[4] = dot2x4(vw[4][c], hvc, a[4]);
      a[5] = dot2x4(vA, hvc, a[5]);
      a[6] = dot2x4(vB, hvc, a[6]);
      a[7] = dot2x4(vC, hvc, a[7]);
    }
    // reduce-scatter: row 8R8+(W&7) total lands in every lane of its group
    float b4[4];
    {
      const bool s0 = (W & 1);
      #pragma unroll
      for (int i = 0; i < 4; i++) {
        float keep = s0 ? a[2*i+1] : a[2*i];
        float send = s0 ? a[2*i]   : a[2*i+1];
        b4[i] = keep + dpp_xorf<0xB1>(send);   // quad_perm(1,0,3,2) = xor1
      }
    }
    float c2[2];
    {
      const bool s1 = (W >> 1) & 1;
      #pragma unroll
      for (int i = 0; i < 2; i++) {
        float keep = s1 ? b4[2*i+1] : b4[2*i];
        float send = s1 ? b4[2*i]   : b4[2*i+1];
        c2[i] = keep + dpp_xorf<0x4E>(send);   // quad_perm(2,3,0,1) = xor2
      }
    }
    float s;
    {
      const bool s2 = (W >> 2) & 1;
      float keep = s2 ? c2[1] : c2[0];
      float send = s2 ? c2[0] : c2[1];
      s = keep + __shfl_xor(send, 4);
    }
    s += __shfl_xor(s, 8);
    s += __shfl_xor(s, 16);
    if (W < 8) {
      int row = 8*R8 + W;                         // 0..127
      int idx = ((row & 63) << 1) | (row >> 6);   // packed (g, g+64) halves
      ((uint16_t*)svh32)[idx] = f16b(s);
    }
    lds_barrier();

    // ---- phase B: rows d=2l,2l+1; svh quad-read + DPP broadcast; U streamed
    //      from the coalesced uqs layout (words 0..51) + ulds (52..63) ----
    float p0 = 0.f, p1 = 0.f;
    { // q0: words 0..15
      uint4 u00 = uqs4[0*512 + l],  u01 = uqs4[1*512 + l],
            u02 = uqs4[2*512 + l],  u03 = uqs4[3*512 + l];
      uint4 u10 = uqs4[13*512 + l], u11 = uqs4[14*512 + l],
            u12 = uqs4[15*512 + l], u13 = uqs4[16*512 + l];
      uint4 svm = svh4[m]; uint4 sv;
      sv = qbcast4<0>(svm); p0 = dot2x4(u00, sv, p0); p1 = dot2x4(u10, sv, p1);
      sv = qbcast4<1>(svm); p0 = dot2x4(u01, sv, p0); p1 = dot2x4(u11, sv, p1);
      sv = qbcast4<2>(svm); p0 = dot2x4(u02, sv, p0); p1 = dot2x4(u12, sv, p1);
      sv = qbcast4<3>(svm); p0 = dot2x4(u03, sv, p0); p1 = dot2x4(u13, sv, p1);
    }
    { // q1: words 16..31
      uint4 u00 = uqs4[4*512 + l],  u01 = uqs4[5*512 + l],
            u02 = uqs4[6*512 + l],  u03 = uqs4[7*512 + l];
      uint4 u10 = uqs4[17*512 + l], u11 = uqs4[18*512 + l],
            u12 = uqs4[19*512 + l], u13 = uqs4[20*512 + l];
      uint4 svm = svh4[4 + m]; uint4 sv;
      sv = qbcast4<0>(svm); p0 = dot2x4(u00, sv, p0); p1 = dot2x4(u10, sv, p1);
      sv = qbcast4<1>(svm); p0 = dot2x4(u01, sv, p0); p1 = dot2x4(u11, sv, p1);
      sv = qbcast4<2>(svm); p0 = dot2x4(u02, sv, p0); p1 = dot2x4(u12, sv, p1);
      sv = qbcast4<3>(svm); p0 = dot2x4(u03, sv, p0); p1 = dot2x4(u13, sv, p1);
    }
    { // q2: words 32..47
      uint4 u00 = uqs4[8*512 + l],  u01 = uqs4[9*512 + l],
            u02 = uqs4[10*512 + l], u03 = uqs4[11*512 + l];
      uint4 u10 = uqs4[21*512 + l], u11 = uqs4[22*512 + l],
            u12 = uqs4[23*512 + l], u13 = uqs4[24*512 + l];
      uint4 svm = svh4[8 + m]; uint4 sv;
      sv = qbcast4<0>(svm); p0 = dot2x4(u00, sv, p0); p1 = dot2x4(u10, sv, p1);
      sv = qbcast4<1>(svm); p0 = dot2x4(u01, sv, p0); p1 = dot2x4(u11, sv, p1);
      sv = qbcast4<2>(svm); p0 = dot2x4(u02, sv, p0); p1 = dot2x4(u12, sv, p1);
      sv = qbcast4<3>(svm); p0 = dot2x4(u03, sv, p0); p1 = dot2x4(u13, sv, p1);
    }
    { // q3: words 48..51 streamed + 52..63 from ulds
      uint4 u0a = uqs4[12*512 + l];
      uint4 u1a = uqs4[25*512 + l];
      uint4 u0b = ulds[0*512 + l], u0c = ulds[1*512 + l], u0d = ulds[2*512 + l];
      uint4 u1b = ulds[3*512 + l], u1c = ulds[4*512 + l], u1d = ulds[5*512 + l];
      uint4 svm = svh4[12 + m]; uint4 sv;
      sv = qbcast4<0>(svm); p0 = dot2x4(u0a, sv, p0); p1 = dot2x4(u1a, sv, p1);
      sv = qbcast4<1>(svm); p0 = dot2x4(u0b, sv, p0); p1 = dot2x4(u1b, sv, p1);
      sv = qbcast4<2>(svm); p0 = dot2x4(u0c, sv, p0); p1 = dot2x4(u1c, sv, p1);
      sv = qbcast4<3>(svm); p0 = dot2x4(u0d, sv, p0); p1 = dot2x4(u1d, sv, p1);
    }

    float hv0 = fast_tanh(p0 + cc.x);
    float hv1 = fast_tanh(p1 + cc.y);
    *cp2 = make_float2(hv0, hv1);                             // h[t+1] (f32 out)
    ((uint32_t*)hbuf)[20*(l>>4) + (l&15)] = pack2(hv0, hv1);  // h for next step
    *op2 = make_float2(hv0 * fast_silu(zz.x), hv1 * fast_silu(zz.y));
    lds_barrier();

    cp2 += BD/2; zp2 += BD/2; op2 += BD/2;
  }
}

extern "C" void kernel_launch(void* const* d_in, const int* in_sizes, int n_in,
                              void* d_out, int out_size, void* d_ws, size_t ws_size,
                              hipStream_t stream) {
  const float* x  = (const float*)d_in[0];
  const float* z  = (const float*)d_in[1];
  const float* h0 = (const float*)d_in[2];
  const float* Uh = (const float*)d_in[3];
  const float* Vh = (const float*)d_in[4];
  const float* sh = (const float*)d_in[5];
  const float* Ux = (const float*)d_in[6];
  const float* Vx = (const float*)d_in[7];
  const float* sx = (const float*)d_in[8];
  const float* bb = (const float*)d_in[9];
  float* outb = (float*)d_out;
  uint32_t* ws32 = (uint32_t*)d_ws;   // needs 1 MiB

  prep_kernel<<<512, 256, 0, stream>>>(Uh, Vh, sh, Ux, Vx, sx, h0, ws32, outb + TBD);
  inp_kernel<<<T_STEPS, 512, 0, stream>>>(x, ws32, bb, outb + TBD);
  rec_kernel<<<BATCH, 512, 0, stream>>>(ws32, z, outb);
}

// Round 14
// 2468.164 us; speedup vs baseline: 1.3453x; 1.3453x over previous
//
#include <hip/hip_runtime.h>
#include <cstdint>

#define T_STEPS 1024
#define BATCH   32
#define DIM     1024
#define RANK    128
#define BD      (BATCH*DIM)            // 32768
#define TBD     ((size_t)T_STEPS*BD)   // 33554432

typedef _Float16 half2v __attribute__((ext_vector_type(2)));

__device__ __forceinline__ float dot2f(uint32_t a, uint32_t b, float acc) {
#if __has_builtin(__builtin_amdgcn_fdot2)
  return __builtin_amdgcn_fdot2(__builtin_bit_cast(half2v, a),
                                __builtin_bit_cast(half2v, b), acc, false);
#else
  half2v xx = __builtin_bit_cast(half2v, a);
  half2v yy = __builtin_bit_cast(half2v, b);
  return acc + (float)xx[0]*(float)yy[0] + (float)xx[1]*(float)yy[1];
#endif
}

__device__ __forceinline__ float dot2x4(uint4 w, uint4 h, float acc) {
  acc = dot2f(w.x, h.x, acc); acc = dot2f(w.y, h.y, acc);
  acc = dot2f(w.z, h.z, acc); acc = dot2f(w.w, h.w, acc);
  return acc;
}

__device__ __forceinline__ uint16_t f16b(float x) {
  _Float16 h = (_Float16)x;
  return __builtin_bit_cast(unsigned short, h);
}
__device__ __forceinline__ uint32_t pack2(float a, float b) {
  return (uint32_t)f16b(a) | ((uint32_t)f16b(b) << 16);
}
__device__ __forceinline__ float fast_tanh(float x) {
  float e = __expf(2.0f*x);
  return 1.0f - 2.0f/(e + 1.0f);
}
__device__ __forceinline__ float fast_silu(float zz) {
  return zz / (1.0f + __expf(-zz));
}

__device__ __forceinline__ void pin4(uint4 &v) {
  asm volatile("" : "+v"(v.x), "+v"(v.y), "+v"(v.z), "+v"(v.w));
}

// quad_perm broadcast of lane K (0..3) within each quad — VALU pipe, no LDS.
template<int K>
__device__ __forceinline__ uint32_t qbcast(uint32_t v) {
  return (uint32_t)__builtin_amdgcn_mov_dpp((int)v, K*0x55, 0xf, 0xf, true);
}
template<int K>
__device__ __forceinline__ uint4 qbcast4(uint4 v) {
  uint4 r;
  r.x = qbcast<K>(v.x); r.y = qbcast<K>(v.y);
  r.z = qbcast<K>(v.z); r.w = qbcast<K>(v.w);
  return r;
}
template<int CTRL>
__device__ __forceinline__ float dpp_xorf(float v) {
  int t = __builtin_amdgcn_mov_dpp(__builtin_bit_cast(int, v), CTRL, 0xf, 0xf, true);
  return __builtin_bit_cast(float, t);
}

// barrier that does NOT drain vmcnt (only LDS ordering needed between phases)
__device__ __forceinline__ void lds_barrier() {
  asm volatile("s_waitcnt lgkmcnt(0)" ::: "memory");
  __builtin_amdgcn_s_barrier();
  __builtin_amdgcn_sched_barrier(0);
}

// ---------------------------------------------------------------------------
// K0: pack weights to f16 pairs in ws (s folded into U), h0 -> h-slot 0.
// ws layout (uint32 words):
//   [0]      vhw  [128][512]   V_h f16 pairs (word = adjacent d-pair)
//   [65536]  uqs  [26][512][4] U'_h STREAM layout (interleaved col pairs):
//                              chunk J<13: row 2*lane words 4J..4J+3
//                              chunk J>=13: row 2*lane+1 words 4(J-13)..+3
//                              (words 0..51 only; lane-stride 16B = coalesced)
//   [118784] ures [1024][12]   U'_h words 52..63 (row-major; rec stages to LDS)
//   [131072] vxw  [128][512]
//   [196608] uxw  [1024][64]   (plain pair layout, used by inp_kernel)
// U'_h word k of row d = pack(U[d][k]*s[k], U[d][k+64]*s[k+64]).
// ---------------------------------------------------------------------------
__global__ void prep_kernel(const float* __restrict__ Uh, const float* __restrict__ Vh,
                            const float* __restrict__ sh, const float* __restrict__ Ux,
                            const float* __restrict__ Vx, const float* __restrict__ sx,
                            const float* __restrict__ h0, uint32_t* __restrict__ ws32,
                            float* __restrict__ hout) {
  int i = blockIdx.x*blockDim.x + threadIdx.x;
  int n = gridDim.x*blockDim.x;
  for (int p = i; p < 65536; p += n) {
    int r = p >> 9, dp = p & 511;
    ws32[p] = pack2(Vh[r*1024 + 2*dp], Vh[r*1024 + 2*dp + 1]);
  }
  for (int p = i; p < 65536; p += n) {
    int d = p >> 6, k = p & 63;
    uint32_t w = pack2(Uh[d*128 + k]      * sh[k],
                       Uh[d*128 + 64 + k] * sh[64 + k]);
    if (k < 52) {
      int J = (k >> 2) + 13*(d & 1);
      ws32[65536 + J*2048 + (d >> 1)*4 + (k & 3)] = w;
    } else {
      ws32[118784 + d*12 + (k - 52)] = w;
    }
  }
  for (int p = i; p < 65536; p += n) {
    int r = p >> 9, dp = p & 511;
    ws32[131072 + p] = pack2(Vx[r*1024 + 2*dp], Vx[r*1024 + 2*dp + 1]);
  }
  for (int p = i; p < 65536; p += n) {
    int d = p >> 6, rp = p & 63;
    ws32[196608 + p] = pack2(Ux[d*128 + 2*rp]   * sx[2*rp],
                             Ux[d*128 + 2*rp+1] * sx[2*rp+1]);
  }
  for (int p = i; p < BD; p += n) hout[p] = h0[p];
}

// ---------------------------------------------------------------------------
// K1: input branch. One WG per timestep t. (unchanged)
// ---------------------------------------------------------------------------
__global__ __launch_bounds__(512, 4) void inp_kernel(
    const float* __restrict__ x, const uint32_t* __restrict__ ws32,
    const float* __restrict__ bias, float* __restrict__ hout) {
  const int t = blockIdx.x;
  const int l = threadIdx.x;  // 0..511
  __shared__ __attribute__((aligned(16))) uint32_t xs[32*516];
  __shared__ __attribute__((aligned(16))) uint16_t svx[BATCH*RANK];

  const float4* xg = (const float4*)(x + (size_t)t*BD);
  #pragma unroll
  for (int k = 0; k < 16; k++) {
    int i = l + 512*k;
    float4 v = xg[i];
    int bb = i >> 8;
    int d4 = i & 255;
    xs[bb*516 + d4*2]     = pack2(v.x, v.y);
    xs[bb*516 + d4*2 + 1] = pack2(v.z, v.w);
  }
  __syncthreads();

  const int q4 = l & 3;
  const int r  = l >> 2;
  const uint4* wrow = (const uint4*)(ws32 + 131072 + r*512);
  float acc0[8], acc1[8];
  #pragma unroll
  for (int bi = 0; bi < 8; bi++) { acc0[bi] = 0.f; acc1[bi] = 0.f; }
  #pragma unroll 4
  for (int J = 0; J < 128; J += 2) {
    uint4 w0 = wrow[J];
    uint4 w1 = wrow[J+1];
    #pragma unroll
    for (int bi = 0; bi < 8; bi++) {
      const uint4* xrow = (const uint4*)(xs + (4*bi + q4)*516);
      uint4 h0v = xrow[J];
      acc0[bi] = dot2f(w0.x, h0v.x, acc0[bi]);
      acc0[bi] = dot2f(w0.y, h0v.y, acc0[bi]);
      acc0[bi] = dot2f(w0.z, h0v.z, acc0[bi]);
      acc0[bi] = dot2f(w0.w, h0v.w, acc0[bi]);
      uint4 h1v = xrow[J+1];
      acc1[bi] = dot2f(w1.x, h1v.x, acc1[bi]);
      acc1[bi] = dot2f(w1.y, h1v.y, acc1[bi]);
      acc1[bi] = dot2f(w1.z, h1v.z, acc1[bi]);
      acc1[bi] = dot2f(w1.w, h1v.w, acc1[bi]);
    }
  }
  #pragma unroll
  for (int bi = 0; bi < 8; bi++)
    svx[(4*bi + q4)*RANK + r] = f16b(acc0[bi] + acc1[bi]);
  __syncthreads();

  const uint4* svx4 = (const uint4*)svx;
  float accb[BATCH];
  #pragma unroll 1
  for (int dd = 0; dd < 2; dd++) {
    int d = l + dd*512;
    const uint4* urow = (const uint4*)(ws32 + 196608 + d*64);
    #pragma unroll
    for (int bi = 0; bi < BATCH; bi++) accb[bi] = 0.f;
    #pragma unroll
    for (int RP = 0; RP < 16; RP++) {
      uint4 w = urow[RP];
      #pragma unroll
      for (int bi = 0; bi < BATCH; bi++) {
        uint4 sv = svx4[bi*16 + RP];
        accb[bi] = dot2f(w.x, sv.x, accb[bi]);
        accb[bi] = dot2f(w.y, sv.y, accb[bi]);
        accb[bi] = dot2f(w.z, sv.z, accb[bi]);
        accb[bi] = dot2f(w.w, sv.w, accb[bi]);
      }
    }
    float bv = bias[d];
    float* cslot = hout + (size_t)(t+1)*BD + d;
    #pragma unroll
    for (int bi = 0; bi < BATCH; bi++)
      cslot[(size_t)bi*DIM] = accb[bi] + bv;
  }
}

// ---------------------------------------------------------------------------
// K2: recurrence v14 = R9's EXACT structure (best: 1952us) with only the U
// source changed: uq0/uq1 arrays (now 13 uint4 each, loaded BEFORE the t-loop
// so the allocator remats them at use -> R9's proven hoisted-load schedule)
// read from the coalesced uqs layout; U words 52..63 come from ulds (48 KB,
// staged once). Stream 256 -> 208 KB/step. v13's regression was the inline
// per-quarter loads (serialized L2 latency, VGPR=100); this keeps R9's form.
//   regs  80 w: V rows 8R8+0..4 (pinned)   LDS 147 KB: V rows 5..7 + U 52..63
// ---------------------------------------------------------------------------
__global__ __attribute__((amdgpu_flat_work_group_size(512, 512),
                          amdgpu_waves_per_eu(2, 2)))
void rec_kernel(
    const uint32_t* __restrict__ ws32, const float* __restrict__ z,
    float* __restrict__ outb) {
  const int b  = blockIdx.x;
  const int l  = threadIdx.x;  // 0..511
  const int W  = l & 31;
  const int R8 = l >> 5;       // 0..15
  const int m  = l & 3;
  float* hout = outb + TBD;
  const uint4* vhw4  = (const uint4*)ws32;             // V: row stride 128 uint4
  const uint4* uqs4  = (const uint4*)(ws32 + 65536);   // stream chunks [26][512]
  const uint4* ures4 = (const uint4*)(ws32 + 118784);  // [1024][3] words 52..63

  __shared__ __attribute__((aligned(16))) uint4    vlds[6144];   // 96 KB
  __shared__ __attribute__((aligned(16))) uint4    ulds[3072];   // 48 KB
  __shared__ __attribute__((aligned(16))) uint4    hbuf[32*5];   // 2.5 KB staggered
  __shared__ __attribute__((aligned(16))) uint32_t svh32[64];    // 256 B

  // V rows 8R8+0..4, window [16W,16W+16) pairs -> VGPRs (80 words, pinned)
  uint4 vw[5][4];
  #pragma unroll
  for (int r = 0; r < 5; r++) {
    #pragma unroll
    for (int c = 0; c < 4; c++) vw[r][c] = vhw4[(8*R8 + r)*128 + W*4 + c];
  }
  #pragma unroll
  for (int r = 0; r < 5; r++) {
    #pragma unroll
    for (int c = 0; c < 4; c++) pin4(vw[r][c]);
  }
  // V rows 8R8+5,6,7 -> vlds (interleaved: idx = R8*384 + rr*128 + c*32 + W)
  #pragma unroll
  for (int rr = 0; rr < 3; rr++) {
    #pragma unroll
    for (int c = 0; c < 4; c++)
      vlds[R8*384 + rr*128 + c*32 + W] = vhw4[(8*R8 + 5 + rr)*128 + W*4 + c];
  }
  // U words 52..63 of rows 2l (slots 0..2) and 2l+1 (slots 3..5) -> ulds
  #pragma unroll
  for (int j = 0; j < 3; j++) {
    ulds[j*512 + l]     = ures4[(2*l)*3 + j];
    ulds[(3+j)*512 + l] = ures4[(2*l+1)*3 + j];
  }
  // U words 0..51 -> arrays BEFORE the loop (R9 style: allocator remats
  // these as hoisted loads inside phase B each iteration)
  uint4 uq0[13], uq1[13];
  #pragma unroll
  for (int J = 0; J < 13; J++) {
    uq0[J] = uqs4[J*512 + l];
    uq1[J] = uqs4[(13+J)*512 + l];
  }
  // init hbuf from h0 (pair p=l at word 20*(p>>4) + (p&15))
  {
    const float2 v = ((const float2*)(hout + (size_t)b*DIM))[l];
    ((uint32_t*)hbuf)[20*(l>>4) + (l&15)] = pack2(v.x, v.y);
  }
  __syncthreads();

  const float2* zp2 = (const float2*)(z + (size_t)b*DIM) + l;
  float2*       cp2 = (float2*)(hout + BD + (size_t)b*DIM) + l;
  float2*       op2 = (float2*)(outb + (size_t)b*DIM) + l;
  const uint4*  hb4  = hbuf + W*5;
  const uint4*  svh4 = (const uint4*)svh32;
  const int vbase = R8*384;

  #pragma unroll 1
  for (int t = 0; t < T_STEPS; t++) {
    // ---- issue c (slot t+1) and z (slot t) loads: consumed in phase B ----
    float2 cc = *cp2;
    float2 zz = *zp2;

    // ---- phase A: 8 rows (5 reg + 3 LDS) x 16-pair window ----
    float a[8] = {0.f,0.f,0.f,0.f,0.f,0.f,0.f,0.f};
    #pragma unroll
    for (int c = 0; c < 4; c++) {
      uint4 hvc = hb4[c];
      uint4 vA = vlds[vbase + c*32 + W];
      uint4 vB = vlds[vbase + 128 + c*32 + W];
      uint4 vC = vlds[vbase + 256 + c*32 + W];
      a[0] = dot2x4(vw[0][c], hvc, a[0]);
      a[1] = dot2x4(vw[1][c], hvc, a[1]);
      a[2] = dot2x4(vw[2][c], hvc, a[2]);
      a[3] = dot2x4(vw[3][c], hvc, a[3]);
      a[4] = dot2x4(vw[4][c], hvc, a[4]);
      a[5] = dot2x4(vA, hvc, a[5]);
      a[6] = dot2x4(vB, hvc, a[6]);
      a[7] = dot2x4(vC, hvc, a[7]);
    }
    // reduce-scatter: row 8R8+(W&7) total lands in every lane of its group
    float b4[4];
    {
      const bool s0 = (W & 1);
      #pragma unroll
      for (int i = 0; i < 4; i++) {
        float keep = s0 ? a[2*i+1] : a[2*i];
        float send = s0 ? a[2*i]   : a[2*i+1];
        b4[i] = keep + dpp_xorf<0xB1>(send);   // quad_perm(1,0,3,2) = xor1
      }
    }
    float c2[2];
    {
      const bool s1 = (W >> 1) & 1;
      #pragma unroll
      for (int i = 0; i < 2; i++) {
        float keep = s1 ? b4[2*i+1] : b4[2*i];
        float send = s1 ? b4[2*i]   : b4[2*i+1];
        c2[i] = keep + dpp_xorf<0x4E>(send);   // quad_perm(2,3,0,1) = xor2
      }
    }
    float s;
    {
      const bool s2 = (W >> 2) & 1;
      float keep = s2 ? c2[1] : c2[0];
      float send = s2 ? c2[0] : c2[1];
      s = keep + __shfl_xor(send, 4);
    }
    s += __shfl_xor(s, 8);
    s += __shfl_xor(s, 16);
    if (W < 8) {
      int row = 8*R8 + W;                         // 0..127
      int idx = ((row & 63) << 1) | (row >> 6);   // packed (g, g+64) halves
      ((uint16_t*)svh32)[idx] = f16b(s);
    }
    lds_barrier();

    // ---- phase B: rows d=2l,2l+1; svh quad-read + DPP broadcast ----
    float p0 = 0.f, p1 = 0.f;
    { // quarter 0: uint4 0..3
      uint4 svm = svh4[m];
      uint4 sv;
      sv = qbcast4<0>(svm); p0 = dot2x4(uq0[0], sv, p0); p1 = dot2x4(uq1[0], sv, p1);
      sv = qbcast4<1>(svm); p0 = dot2x4(uq0[1], sv, p0); p1 = dot2x4(uq1[1], sv, p1);
      sv = qbcast4<2>(svm); p0 = dot2x4(uq0[2], sv, p0); p1 = dot2x4(uq1[2], sv, p1);
      sv = qbcast4<3>(svm); p0 = dot2x4(uq0[3], sv, p0); p1 = dot2x4(uq1[3], sv, p1);
    }
    { // quarter 1: uint4 4..7
      uint4 svm = svh4[4 + m];
      uint4 sv;
      sv = qbcast4<0>(svm); p0 = dot2x4(uq0[4], sv, p0); p1 = dot2x4(uq1[4], sv, p1);
      sv = qbcast4<1>(svm); p0 = dot2x4(uq0[5], sv, p0); p1 = dot2x4(uq1[5], sv, p1);
      sv = qbcast4<2>(svm); p0 = dot2x4(uq0[6], sv, p0); p1 = dot2x4(uq1[6], sv, p1);
      sv = qbcast4<3>(svm); p0 = dot2x4(uq0[7], sv, p0); p1 = dot2x4(uq1[7], sv, p1);
    }
    { // quarter 2: uint4 8..11
      uint4 svm = svh4[8 + m];
      uint4 sv;
      sv = qbcast4<0>(svm); p0 = dot2x4(uq0[8],  sv, p0); p1 = dot2x4(uq1[8],  sv, p1);
      sv = qbcast4<1>(svm); p0 = dot2x4(uq0[9],  sv, p0); p1 = dot2x4(uq1[9],  sv, p1);
      sv = qbcast4<2>(svm); p0 = dot2x4(uq0[10], sv, p0); p1 = dot2x4(uq1[10], sv, p1);
      sv = qbcast4<3>(svm); p0 = dot2x4(uq0[11], sv, p0); p1 = dot2x4(uq1[11], sv, p1);
    }
    { // quarter 3: uint4 12 streamed + words 52..63 from ulds
      uint4 u0b = ulds[0*512 + l], u0c = ulds[1*512 + l], u0d = ulds[2*512 + l];
      uint4 u1b = ulds[3*512 + l], u1c = ulds[4*512 + l], u1d = ulds[5*512 + l];
      uint4 svm = svh4[12 + m];
      uint4 sv;
      sv = qbcast4<0>(svm); p0 = dot2x4(uq0[12], sv, p0); p1 = dot2x4(uq1[12], sv, p1);
      sv = qbcast4<1>(svm); p0 = dot2x4(u0b, sv, p0); p1 = dot2x4(u1b, sv, p1);
      sv = qbcast4<2>(svm); p0 = dot2x4(u0c, sv, p0); p1 = dot2x4(u1c, sv, p1);
      sv = qbcast4<3>(svm); p0 = dot2x4(u0d, sv, p0); p1 = dot2x4(u1d, sv, p1);
    }

    float hv0 = fast_tanh(p0 + cc.x);
    float hv1 = fast_tanh(p1 + cc.y);
    *cp2 = make_float2(hv0, hv1);                             // h[t+1] (f32 out)
    ((uint32_t*)hbuf)[20*(l>>4) + (l&15)] = pack2(hv0, hv1);  // h for next step
    *op2 = make_float2(hv0 * fast_silu(zz.x), hv1 * fast_silu(zz.y));
    lds_barrier();

    cp2 += BD/2; zp2 += BD/2; op2 += BD/2;
  }
}

extern "C" void kernel_launch(void* const* d_in, const int* in_sizes, int n_in,
                              void* d_out, int out_size, void* d_ws, size_t ws_size,
                              hipStream_t stream) {
  const float* x  = (const float*)d_in[0];
  const float* z  = (const float*)d_in[1];
  const float* h0 = (const float*)d_in[2];
  const float* Uh = (const float*)d_in[3];
  const float* Vh = (const float*)d_in[4];
  const float* sh = (const float*)d_in[5];
  const float* Ux = (const float*)d_in[6];
  const float* Vx = (const float*)d_in[7];
  const float* sx = (const float*)d_in[8];
  const float* bb = (const float*)d_in[9];
  float* outb = (float*)d_out;
  uint32_t* ws32 = (uint32_t*)d_ws;   // needs 1 MiB

  prep_kernel<<<512, 256, 0, stream>>>(Uh, Vh, sh, Ux, Vx, sx, h0, ws32, outb + TBD);
  inp_kernel<<<T_STEPS, 512, 0, stream>>>(x, ws32, bb, outb + TBD);
  rec_kernel<<<BATCH, 512, 0, stream>>>(ws32, z, outb);
}